// Round 2
// baseline (416.936 us; speedup 1.0000x reference)
//
#include <hip/hip_runtime.h>
#include <hip/hip_bf16.h>

typedef __bf16 bf16_t;
typedef __bf16 bf16x8 __attribute__((ext_vector_type(8)));
typedef float  f32x4  __attribute__((ext_vector_type(4)));

#define BS 512
#define LH 100
#define NC 64
#define DD 256
#define IC 256
#define KK 32

// workspace layout (bytes), peak 23,330,816 (proven-safe):
//  [0, 6,553,600)          S fp32 -> attn fp32 in-place -> wm fp32
//  [6,553,600, +393,216)   W bf16 planes (dead after k12)
//  [6,946,816, +49,152)    C bf16 planes (dead after k12)
//  [6,553,600, 23,330,816) I fp32 (k4 writes; overlaps dead planes)
#define OFF_WPL 6553600
#define OFF_CPL (6553600 + 3 * 131072)
#define OFF_I   6553600

// split fp32 into 3 bf16 terms: v == h + l + l2 exactly
__device__ __forceinline__ void split3(float v, bf16_t& h, bf16_t& l, bf16_t& l2) {
    h = (bf16_t)v;  float r1 = v - (float)h;
    l = (bf16_t)r1; float r2 = r1 - (float)l;
    l2 = (bf16_t)r2;
}

__device__ __forceinline__ void split3x8(const float* v, bf16x8& h, bf16x8& l, bf16x8& l2) {
#pragma unroll
    for (int j = 0; j < 8; j++) {
        bf16_t a, b, c;
        split3(v[j], a, b, c);
        h[j] = a; l[j] = b; l2[j] = c;
    }
}

// fp32-faithful 16x16x32 MFMA: 6 kept terms, main in accM, corrections in accC
__device__ __forceinline__ void mfma6(const bf16x8& ah, const bf16x8& al, const bf16x8& al2,
                                      const bf16x8& bh, const bf16x8& bl, const bf16x8& bl2,
                                      f32x4& accM, f32x4& accC) {
    accM = __builtin_amdgcn_mfma_f32_16x16x32_bf16(ah,  bh,  accM, 0, 0, 0);
    accC = __builtin_amdgcn_mfma_f32_16x16x32_bf16(ah,  bl,  accC, 0, 0, 0);
    accC = __builtin_amdgcn_mfma_f32_16x16x32_bf16(al,  bh,  accC, 0, 0, 0);
    accC = __builtin_amdgcn_mfma_f32_16x16x32_bf16(ah,  bl2, accC, 0, 0, 0);
    accC = __builtin_amdgcn_mfma_f32_16x16x32_bf16(al,  bl,  accC, 0, 0, 0);
    accC = __builtin_amdgcn_mfma_f32_16x16x32_bf16(al2, bh,  accC, 0, 0, 0);
}

// ---------------------------------------------------------------------------
// fast fp64 tanh: relative error < ~1e-15, so (float)result matches
// (float)tanh((double)x) except ~1e-7 of inputs by 1 float ulp.
// ---------------------------------------------------------------------------
__device__ __forceinline__ float fast_tanh_f32(float xf) {
    const double t  = fabs((double)xf) * 2.0;              // t = 2|x| >= 0
    const double nf = rint(t * 1.4426950408889634);        // n = rint(t/ln2)
    double r = fma(nf, -6.93147180369123816490e-01, t);
    r = fma(nf, -1.90821492927058770002e-10, r);           // r in [-0.3466, 0.3466]
    const double r2 = r * r;
    double p =        2.08767569878680989792e-09;          // 1/12!
    p = fma(p, r,     2.50521083854417187751e-08);
    p = fma(p, r,     2.75573192239858906526e-07);
    p = fma(p, r,     2.75573192239858925110e-06);
    p = fma(p, r,     2.48015873015873015873e-05);
    p = fma(p, r,     1.98412698412698412526e-04);
    p = fma(p, r,     1.38888888888888894069e-03);
    p = fma(p, r,     8.33333333333333321769e-03);
    p = fma(p, r,     4.16666666666666643537e-02);
    p = fma(p, r,     1.66666666666666657415e-01);
    p = fma(p, r,     5.00000000000000000000e-01);
    const double q   = fma(r2, p, r);                      // expm1(r), no cancellation
    const double s   = ldexp(1.0, (int)nf);                // 2^n
    const double em1 = fma(s, q, s - 1.0);                 // e^t - 1
    double ti = em1 / (em1 + 2.0);                         // tanh(|x|)
    if (t > 20.0) ti = 1.0;
    return copysignf((float)ti, xf);
}

// ---------------------------------------------------------------------------
// KP: pre-split W (65536) and C (8192) fp32 -> 3 bf16 planes each
// ---------------------------------------------------------------------------
__global__ __launch_bounds__(256) void kp_split(const float* __restrict__ W,
                                                const float* __restrict__ C,
                                                bf16_t* __restrict__ Wh, bf16_t* __restrict__ Wl,
                                                bf16_t* __restrict__ Wl2,
                                                bf16_t* __restrict__ Ch, bf16_t* __restrict__ Cl,
                                                bf16_t* __restrict__ Cl2) {
    int idx = blockIdx.x * 256 + threadIdx.x;
    if (idx < 65536) {
        bf16_t h, l, l2;
        split3(W[idx], h, l, l2);
        Wh[idx] = h; Wl[idx] = l; Wl2[idx] = l2;
    } else {
        int i = idx - 65536;
        if (i < 8192) {
            bf16_t h, l, l2;
            split3(C[i], h, l, l2);
            Ch[i] = h; Cl[i] = l; Cl2[i] = l2;
        }
    }
}

// ---------------------------------------------------------------------------
// K12: P = tanh(H W^T) (fp32-faithful), S = P C^T (fp32-faithful).
// Changes vs 333us version (values & accumulation order bit-identical):
//  - 1-wave blocks (64 thr), grid 3200: load-imbalance 28% -> 4%
//    (800 = 3x256+32 forced 32 CUs to run a 4th block while 224 idled).
//  - W planes read DIRECTLY from global (L2-resident, 384KB total): deletes
//    both per-chunk __syncthreads and the W LDS buffer + its 5.3M bank
//    conflicts. Cost: W re-read per wave (~1.2GB L2 traffic ~= 36us floor).
//  - pl transpose round-trip stays wave-local in a 2.2KB LDS block.
// ---------------------------------------------------------------------------
__global__ __launch_bounds__(64, 3) void k12_proj_scores(const float* __restrict__ H,
                                                         const bf16_t* __restrict__ Wh,
                                                         const bf16_t* __restrict__ Wl,
                                                         const bf16_t* __restrict__ Wl2,
                                                         const bf16_t* __restrict__ Ch,
                                                         const bf16_t* __restrict__ Cl,
                                                         const bf16_t* __restrict__ Cl2,
                                                         float* __restrict__ S) {
    __shared__ float myp[16 * 34];   // 2,176 B: per-wave P pair-chunk (transpose trip)

    const int lane = threadIdx.x & 63;
    const int r = lane & 15, q = lane >> 4;
    const int m0 = blockIdx.x * 16;

    // ---- load + split A (16 H rows) once ----
    bf16x8 Ah[8], Al[8], Al2[8];
    {
        const float* arow = H + (size_t)(m0 + r) * DD + q * 8;
#pragma unroll
        for (int ks = 0; ks < 8; ks++) {
            const float* ap = arow + ks * 32;
            float4 u = *(const float4*)ap;
            float4 v = *(const float4*)(ap + 4);
            float av[8] = {u.x, u.y, u.z, u.w, v.x, v.y, v.z, v.w};
            split3x8(av, Ah[ks], Al[ks], Al2[ks]);
        }
    }

    const f32x4 zero = {0.f, 0.f, 0.f, 0.f};
    f32x4 saccM[2], saccC[2];
    saccM[0] = zero; saccM[1] = zero; saccC[0] = zero; saccC[1] = zero;

    for (int c16 = 0; c16 < 16; c16++) {
        const int w0 = c16 * 16;             // first W row (= P output col) of chunk

        // ---- stage 1: one 16-col P tile, full K, B straight from L2 ----
        f32x4 aM = zero, aC = zero;
        const size_t wbase = (size_t)(w0 + r) * DD + q * 8;
#pragma unroll
        for (int ks = 0; ks < 8; ks++) {
            bf16x8 bh  = *(const bf16x8*)(Wh  + wbase + ks * 32);
            bf16x8 bl  = *(const bf16x8*)(Wl  + wbase + ks * 32);
            bf16x8 bl2 = *(const bf16x8*)(Wl2 + wbase + ks * 32);
            mfma6(Ah[ks], Al[ks], Al2[ks], bh, bl, bl2, aM, aC);
        }

        // ---- tanh -> wave-local pl (transpose LDS round trip, no barrier) ----
        const int colb = (c16 & 1) * 16;
#pragma unroll
        for (int i = 0; i < 4; i++) {
            float s1 = aM[i] + aC[i];
            myp[(q * 4 + i) * 34 + colb + r] = fast_tanh_f32(s1);
        }

        // ---- stage 2 on odd chunks: S += P_pair(32 cols) @ C_pair^T ----
        if (c16 & 1) {
            const int c0 = (c16 >> 1) * 32;
            const float* ps = myp + r * 34 + q * 8;
            float pv[8];
#pragma unroll
            for (int j = 0; j < 8; j++) pv[j] = ps[j];
            bf16x8 ph, plo, pl2;
            split3x8(pv, ph, plo, pl2);
#pragma unroll
            for (int ntS = 0; ntS < 2; ntS++) {
                const size_t base = (size_t)(ntS * 16 + r) * IC + c0 + q * 8;
                bf16x8 ch  = *(const bf16x8*)(Ch  + base);
                bf16x8 cl  = *(const bf16x8*)(Cl  + base);
                bf16x8 cl2 = *(const bf16x8*)(Cl2 + base);
                mfma6(ph, plo, pl2, ch, cl, cl2, saccM[ntS], saccC[ntS]);
            }
        }
    }

#pragma unroll
    for (int ntS = 0; ntS < 2; ntS++)
#pragma unroll
        for (int i = 0; i < 4; i++)
            S[(size_t)(m0 + q * 4 + i) * KK + ntS * 16 + r] = saccM[ntS][i] + saccC[ntS][i];
}

// ---------------------------------------------------------------------------
// K3: softmax over l per (b,k), fp64 math; masked rows -> 1/100. In-place.
// ---------------------------------------------------------------------------
__global__ __launch_bounds__(256) void k3_softmax(float* __restrict__ Sa,
                                                  const int* __restrict__ ni) {
    const int b = blockIdx.x;
    float* Sb = Sa + (size_t)b * LH * KK;
    __shared__ float ls[LH * KK];
    __shared__ double red[8][KK + 1];

    for (int i = threadIdx.x; i < LH * KK; i += 256) ls[i] = Sb[i];
    __syncthreads();

    const int k = threadIdx.x & 31;
    const int grp = threadIdx.x >> 5;
    const int nib = ni[b];

    double vals[13];
    int cnt = 0;
    double vmax = -1e300;
    for (int l = grp; l < LH; l += 8) {
        double v = (double)ls[l * KK + k];
        vals[cnt++] = v;
        vmax = fmax(vmax, v);
    }
    red[grp][k] = vmax;
    __syncthreads();
    if (grp == 0) {
        double m = red[0][k];
        for (int j = 1; j < 8; j++) m = fmax(m, red[j][k]);
        red[0][k] = m;
    }
    __syncthreads();
    const double mx = red[0][k];
    __syncthreads();

    double s = 0.0;
    for (int i = 0; i < cnt; i++) {
        double e = exp(vals[i] - mx);
        vals[i] = e;
        s += e;
    }
    red[grp][k] = s;
    __syncthreads();
    if (grp == 0) {
        double t = 0.0;
        for (int j = 0; j < 8; j++) t += red[j][k];
        red[0][k] = t;
    }
    __syncthreads();
    const double inv = 1.0 / red[0][k];

    float* ab = Sb + k * LH;
    const bool masked = (k >= nib);
    cnt = 0;
    for (int l = grp; l < LH; l += 8) {
        ab[l] = masked ? 0.01f : (float)(vals[cnt] * inv);
        cnt++;
    }
}

// ---------------------------------------------------------------------------
// K4: I[k][d] = sum_l attn[k][l] * H[l][d] (per b), fp32-faithful.
// ---------------------------------------------------------------------------
__global__ __launch_bounds__(256) void k4_interests(const float* __restrict__ attn,
                                                    const float* __restrict__ H,
                                                    float* __restrict__ I) {
    const int b = blockIdx.x;
    __shared__ float ht[256 * 34];   // 34,816 B: H^T chunk [d][l-l0], pad 34

    const int tid = threadIdx.x;
    const int wave = tid >> 6;
    const int lane = tid & 63;
    const int r = lane & 15, q = lane >> 4;

    const float* Ab = attn + (size_t)b * KK * LH;
    const float* Hb = H + (size_t)b * LH * DD;

    const f32x4 zero = {0.f, 0.f, 0.f, 0.f};
    f32x4 accM[8], accC[8];
#pragma unroll
    for (int jj = 0; jj < 8; jj++) { accM[jj] = zero; accC[jj] = zero; }

    for (int ks = 0; ks < 4; ks++) {
        const int l0c = ks * 32;
        __syncthreads();
        // stage transposed H chunk: l in [l0c, l0c+32) -> ht[d][l-l0c]
        for (int u = tid; u < 32 * 64; u += 256) {
            const int l = u >> 6, dg = u & 63;
            float4 v = {0.f, 0.f, 0.f, 0.f};
            if (l0c + l < LH) v = *(const float4*)(Hb + (size_t)(l0c + l) * DD + dg * 4);
            ht[(dg * 4 + 0) * 34 + l] = v.x;
            ht[(dg * 4 + 1) * 34 + l] = v.y;
            ht[(dg * 4 + 2) * 34 + l] = v.z;
            ht[(dg * 4 + 3) * 34 + l] = v.w;
        }
        __syncthreads();

#pragma unroll
        for (int jj = 0; jj < 8; jj++) {
            const int job = wave + jj * 4;
            const int mt = job & 1, nt = job >> 1;
            const int m0 = mt * 16, n0 = nt * 16;
            float av[8], bv[8];
#pragma unroll
            for (int j = 0; j < 8; j++) {
                const int l = l0c + q * 8 + j;
                av[j] = (l < LH) ? Ab[(size_t)(m0 + r) * LH + l] : 0.f;
            }
            const float* hp = ht + (n0 + r) * 34 + q * 8;
#pragma unroll
            for (int j = 0; j < 8; j++) bv[j] = hp[j];
            bf16x8 ah, al, al2, bh, bl, bl2;
            split3x8(av, ah, al, al2);
            split3x8(bv, bh, bl, bl2);
            mfma6(ah, al, al2, bh, bl, bl2, accM[jj], accC[jj]);
        }
    }

#pragma unroll
    for (int jj = 0; jj < 8; jj++) {
        const int job = wave + jj * 4;
        const int mt = job & 1, nt = job >> 1;
        const int m0 = mt * 16, n0 = nt * 16;
#pragma unroll
        for (int i = 0; i < 4; i++)
            I[((size_t)b * KK + m0 + q * 4 + i) * DD + n0 + r] = accM[jj][i] + accC[jj][i];
    }
}

// ---------------------------------------------------------------------------
// K5: w[n][k] = sum_d cand[n][d]*I[k][d] (fp32-faithful) + variable top-k mask.
// ---------------------------------------------------------------------------
__global__ __launch_bounds__(256) void k5_w_topk(const float* __restrict__ cand,
                                                 const float* __restrict__ I,
                                                 const int* __restrict__ cc,
                                                 float* __restrict__ wm) {
    const int b = blockIdx.x;
    const int wave = threadIdx.x >> 6;
    const int lane = threadIdx.x & 63;
    const int r = lane & 15, q = lane >> 4;

    __shared__ float shw[NC][KK + 1];

    const float* Cb = cand + (size_t)b * NC * DD;
    const float* Ib = I + (size_t)b * KK * DD;

    for (int job = wave; job < 8; job += 4) {
        const int mt = job >> 1, nt = job & 1;
        const int m0 = mt * 16, n0 = nt * 16;
        const f32x4 zero = {0.f, 0.f, 0.f, 0.f};
        f32x4 accM = zero, accC = zero;
#pragma unroll
        for (int ks = 0; ks < 8; ks++) {
            const float* ap = Cb + (size_t)(m0 + r) * DD + ks * 32 + q * 8;
            const float* bp = Ib + (size_t)(n0 + r) * DD + ks * 32 + q * 8;
            float4 u1 = *(const float4*)ap;      float4 u2 = *(const float4*)(ap + 4);
            float4 v1 = *(const float4*)bp;      float4 v2 = *(const float4*)(bp + 4);
            float av[8] = {u1.x,u1.y,u1.z,u1.w,u2.x,u2.y,u2.z,u2.w};
            float bv[8] = {v1.x,v1.y,v1.z,v1.w,v2.x,v2.y,v2.z,v2.w};
            bf16x8 ah, al, al2, bh, bl, bl2;
            split3x8(av, ah, al, al2);
            split3x8(bv, bh, bl, bl2);
            mfma6(ah, al, al2, bh, bl, bl2, accM, accC);
        }
#pragma unroll
        for (int i = 0; i < 4; i++) shw[m0 + q * 4 + i][n0 + r] = accM[i] + accC[i];
    }
    __syncthreads();

    if (threadIdx.x < NC) {
        const int n = threadIdx.x;
        int c8 = 8 * cc[b];
        int dynK = 32 - __clz(c8 - 1);
        dynK = min(max(dynK, 1), KK);
        float v[KK];
        for (int k = 0; k < KK; k++) v[k] = shw[n][k];
        float* dst = wm + ((size_t)b * NC + n) * KK;
        for (int k = 0; k < KK; k++) {
            int rank = 0;
            for (int j = 0; j < KK; j++)
                rank += (v[j] > v[k]) || (v[j] == v[k] && j < k);
            dst[k] = (rank < dynK) ? v[k] : 0.f;
        }
    }
}

// ---------------------------------------------------------------------------
// K6: user[n][d] = sum_k wm[n][k] * I[k][d]  (fp32 out)
// ---------------------------------------------------------------------------
__global__ __launch_bounds__(256) void k6_user(const float* __restrict__ I,
                                               const float* __restrict__ wm,
                                               float* __restrict__ out) {
    const int b = blockIdx.x;
    const int d = threadIdx.x;

    float icol[KK];
    const float* src = I + (size_t)b * KK * DD + d;
#pragma unroll
    for (int k = 0; k < KK; k++) icol[k] = src[(size_t)k * DD];

    const float* wb = wm + (size_t)b * NC * KK;
    for (int n = 0; n < NC; n++) {
        const float* wr = wb + n * KK;
        float acc = 0.f;
#pragma unroll
        for (int k = 0; k < KK; k++) acc += wr[k] * icol[k];
        out[((size_t)b * NC + n) * DD + d] = acc;
    }
}

// ---------------------------------------------------------------------------
extern "C" void kernel_launch(void* const* d_in, const int* in_sizes, int n_in,
                              void* d_out, int out_size, void* d_ws, size_t ws_size,
                              hipStream_t stream) {
    const float* hist = (const float*)d_in[0];
    const float* cand = (const float*)d_in[2];
    const int* ni = (const int*)d_in[3];
    const int* cc = (const int*)d_in[4];
    const float* W = (const float*)d_in[5];
    const float* C = (const float*)d_in[6];
    float* out = (float*)d_out;

    char* w8 = (char*)d_ws;
    float*  S   = (float*)(w8 + 0);
    float*  wm  = (float*)(w8 + 0);
    bf16_t* Wh  = (bf16_t*)(w8 + OFF_WPL);
    bf16_t* Wl  = (bf16_t*)(w8 + OFF_WPL + 131072);
    bf16_t* Wl2 = (bf16_t*)(w8 + OFF_WPL + 262144);
    bf16_t* Ch  = (bf16_t*)(w8 + OFF_CPL);
    bf16_t* Cl  = (bf16_t*)(w8 + OFF_CPL + 16384);
    bf16_t* Cl2 = (bf16_t*)(w8 + OFF_CPL + 32768);
    float*  I   = (float*)(w8 + OFF_I);

    kp_split<<<288, 256, 0, stream>>>(W, C, Wh, Wl, Wl2, Ch, Cl, Cl2);
    k12_proj_scores<<<3200, 64, 0, stream>>>(hist, Wh, Wl, Wl2, Ch, Cl, Cl2, S);
    k3_softmax<<<BS, 256, 0, stream>>>(S, ni);
    k4_interests<<<BS, 256, 0, stream>>>(S, hist, I);
    k5_w_topk<<<BS, 256, 0, stream>>>(cand, I, cc, wm);
    k6_user<<<BS, 256, 0, stream>>>(I, wm, out);
}

// Round 3
// 298.762 us; speedup vs baseline: 1.3955x; 1.3955x over previous
//
#include <hip/hip_runtime.h>
#include <hip/hip_bf16.h>

typedef __bf16 bf16_t;
typedef __bf16 bf16x8 __attribute__((ext_vector_type(8)));
typedef float  f32x4  __attribute__((ext_vector_type(4)));

#define BS 512
#define LH 100
#define NC 64
#define DD 256
#define IC 256
#define KK 32

// workspace layout (bytes), peak 23,330,816 (proven-safe):
//  [0, 6,553,600)          S fp32 (k12 out, read by fused kernel)
//  [6,553,600, +393,216)   W bf16 planes
//  [6,946,816, +49,152)    C bf16 planes
#define OFF_WPL 6553600
#define OFF_CPL (6553600 + 3 * 131072)

// split fp32 into 3 bf16 terms: v == h + l + l2 exactly
__device__ __forceinline__ void split3(float v, bf16_t& h, bf16_t& l, bf16_t& l2) {
    h = (bf16_t)v;  float r1 = v - (float)h;
    l = (bf16_t)r1; float r2 = r1 - (float)l;
    l2 = (bf16_t)r2;
}

__device__ __forceinline__ void split3x8(const float* v, bf16x8& h, bf16x8& l, bf16x8& l2) {
#pragma unroll
    for (int j = 0; j < 8; j++) {
        bf16_t a, b, c;
        split3(v[j], a, b, c);
        h[j] = a; l[j] = b; l2[j] = c;
    }
}

// fp32-faithful 16x16x32 MFMA: 6 kept terms, main in accM, corrections in accC
__device__ __forceinline__ void mfma6(const bf16x8& ah, const bf16x8& al, const bf16x8& al2,
                                      const bf16x8& bh, const bf16x8& bl, const bf16x8& bl2,
                                      f32x4& accM, f32x4& accC) {
    accM = __builtin_amdgcn_mfma_f32_16x16x32_bf16(ah,  bh,  accM, 0, 0, 0);
    accC = __builtin_amdgcn_mfma_f32_16x16x32_bf16(ah,  bl,  accC, 0, 0, 0);
    accC = __builtin_amdgcn_mfma_f32_16x16x32_bf16(al,  bh,  accC, 0, 0, 0);
    accC = __builtin_amdgcn_mfma_f32_16x16x32_bf16(ah,  bl2, accC, 0, 0, 0);
    accC = __builtin_amdgcn_mfma_f32_16x16x32_bf16(al,  bl,  accC, 0, 0, 0);
    accC = __builtin_amdgcn_mfma_f32_16x16x32_bf16(al2, bh,  accC, 0, 0, 0);
}

// ---------------------------------------------------------------------------
// fast fp64 tanh: relative error < ~1e-15 (matches OCML tanh to the f32 ulp)
// ---------------------------------------------------------------------------
__device__ __forceinline__ float fast_tanh_f32(float xf) {
    const double t  = fabs((double)xf) * 2.0;              // t = 2|x| >= 0
    const double nf = rint(t * 1.4426950408889634);        // n = rint(t/ln2)
    double r = fma(nf, -6.93147180369123816490e-01, t);
    r = fma(nf, -1.90821492927058770002e-10, r);           // r in [-0.3466, 0.3466]
    const double r2 = r * r;
    double p =        2.08767569878680989792e-09;          // 1/12!
    p = fma(p, r,     2.50521083854417187751e-08);
    p = fma(p, r,     2.75573192239858906526e-07);
    p = fma(p, r,     2.75573192239858925110e-06);
    p = fma(p, r,     2.48015873015873015873e-05);
    p = fma(p, r,     1.98412698412698412526e-04);
    p = fma(p, r,     1.38888888888888894069e-03);
    p = fma(p, r,     8.33333333333333321769e-03);
    p = fma(p, r,     4.16666666666666643537e-02);
    p = fma(p, r,     1.66666666666666657415e-01);
    p = fma(p, r,     5.00000000000000000000e-01);
    const double q   = fma(r2, p, r);                      // expm1(r), no cancellation
    const double s   = ldexp(1.0, (int)nf);                // 2^n
    const double em1 = fma(s, q, s - 1.0);                 // e^t - 1
    double ti = em1 / (em1 + 2.0);                         // tanh(|x|)
    if (t > 20.0) ti = 1.0;
    return copysignf((float)ti, xf);
}

// ---------------------------------------------------------------------------
// KP: pre-split W (65536) and C (8192) fp32 -> 3 bf16 planes each
// ---------------------------------------------------------------------------
__global__ __launch_bounds__(256) void kp_split(const float* __restrict__ W,
                                                const float* __restrict__ C,
                                                bf16_t* __restrict__ Wh, bf16_t* __restrict__ Wl,
                                                bf16_t* __restrict__ Wl2,
                                                bf16_t* __restrict__ Ch, bf16_t* __restrict__ Cl,
                                                bf16_t* __restrict__ Cl2) {
    int idx = blockIdx.x * 256 + threadIdx.x;
    if (idx < 65536) {
        bf16_t h, l, l2;
        split3(W[idx], h, l, l2);
        Wh[idx] = h; Wl[idx] = l; Wl2[idx] = l2;
    } else {
        int i = idx - 65536;
        if (i < 8192) {
            bf16_t h, l, l2;
            split3(C[i], h, l, l2);
            Ch[i] = h; Cl[i] = l; Cl2[i] = l2;
        }
    }
}

// ---------------------------------------------------------------------------
// K12: P = tanh(H W^T) (fp32-faithful), S = P C^T (fp32-faithful).
// REVERTED to the 123us round-1 version: 4-wave blocks with cooperative LDS
// W-staging. (Round-2 experiment proved 1-wave L2-direct reads are
// latency-bound: MfmaUtil 8.5%, 210us.)
// ---------------------------------------------------------------------------
#define WROW 280   // padded LDS row stride in bf16 (560B: 16B-aligned, 2-way banks)
__global__ __launch_bounds__(256) void k12_proj_scores(const float* __restrict__ H,
                                                       const bf16_t* __restrict__ Wh,
                                                       const bf16_t* __restrict__ Wl,
                                                       const bf16_t* __restrict__ Wl2,
                                                       const bf16_t* __restrict__ Ch,
                                                       const bf16_t* __restrict__ Cl,
                                                       const bf16_t* __restrict__ Cl2,
                                                       float* __restrict__ S) {
    __shared__ bf16_t wlds[3 * 16 * WROW];   // 26,880 B
    __shared__ float  pl[4][16 * 34];        //  8,704 B  (per-wave P pair-chunk)

    const int tid = threadIdx.x;
    const int wave = tid >> 6;
    const int lane = tid & 63;
    const int r = lane & 15, q = lane >> 4;
    const int mt = blockIdx.x * 4 + wave;
    const int m0 = mt * 16;

    // ---- load + split A (H rows) once ----
    bf16x8 Ah[8], Al[8], Al2[8];
    {
        const float* arow = H + (size_t)(m0 + r) * DD + q * 8;
#pragma unroll
        for (int ks = 0; ks < 8; ks++) {
            const float* ap = arow + ks * 32;
            float4 u = *(const float4*)ap;
            float4 v = *(const float4*)(ap + 4);
            float av[8] = {u.x, u.y, u.z, u.w, v.x, v.y, v.z, v.w};
            split3x8(av, Ah[ks], Al[ks], Al2[ks]);
        }
    }

    const f32x4 zero = {0.f, 0.f, 0.f, 0.f};
    f32x4 saccM[2], saccC[2];
    saccM[0] = zero; saccM[1] = zero; saccC[0] = zero; saccC[1] = zero;

    float* myp = pl[wave];

    for (int c16 = 0; c16 < 16; c16++) {
        const int w0 = c16 * 16;             // first W row (= P output col) of chunk
        __syncthreads();   // protect wlds of previous chunk
        // ---- cooperative stage of W-plane chunk rows [w0, w0+16) ----
        for (int g = tid; g < 1536; g += 256) {
            const int p = g >> 9, rem = g & 511, row = rem >> 5, grp = rem & 31;
            const bf16_t* src = (p == 0) ? Wh : (p == 1) ? Wl : Wl2;
            bf16x8 v = *(const bf16x8*)(src + (size_t)(w0 + row) * DD + grp * 8);
            *(bf16x8*)(wlds + (p * 16 + row) * WROW + grp * 8) = v;
        }
        __syncthreads();

        // ---- stage 1: one 16-col P tile, full K ----
        f32x4 aM = zero, aC = zero;
#pragma unroll
        for (int ks = 0; ks < 8; ks++) {
            const int rowb = r * WROW + ks * 32 + q * 8;
            bf16x8 bh  = *(const bf16x8*)(wlds + 0 * 16 * WROW + rowb);
            bf16x8 bl  = *(const bf16x8*)(wlds + 1 * 16 * WROW + rowb);
            bf16x8 bl2 = *(const bf16x8*)(wlds + 2 * 16 * WROW + rowb);
            mfma6(Ah[ks], Al[ks], Al2[ks], bh, bl, bl2, aM, aC);
        }

        // ---- tanh -> per-wave pl (wave-local LDS round trip) ----
        const int colb = (c16 & 1) * 16;
#pragma unroll
        for (int i = 0; i < 4; i++) {
            float s1 = aM[i] + aC[i];
            myp[(q * 4 + i) * 34 + colb + r] = fast_tanh_f32(s1);
        }

        // ---- stage 2 on odd chunks: S += P_pair(32 cols) @ C_pair^T ----
        if (c16 & 1) {
            const int c0 = (c16 >> 1) * 32;
            const float* ps = myp + r * 34 + q * 8;
            float pv[8];
#pragma unroll
            for (int j = 0; j < 8; j++) pv[j] = ps[j];
            bf16x8 ph, plo, pl2;
            split3x8(pv, ph, plo, pl2);
#pragma unroll
            for (int ntS = 0; ntS < 2; ntS++) {
                const size_t base = (size_t)(ntS * 16 + r) * IC + c0 + q * 8;
                bf16x8 ch  = *(const bf16x8*)(Ch  + base);
                bf16x8 cl  = *(const bf16x8*)(Cl  + base);
                bf16x8 cl2 = *(const bf16x8*)(Cl2 + base);
                mfma6(ph, plo, pl2, ch, cl, cl2, saccM[ntS], saccC[ntS]);
            }
        }
    }

#pragma unroll
    for (int ntS = 0; ntS < 2; ntS++)
#pragma unroll
        for (int i = 0; i < 4; i++)
            S[(size_t)(m0 + q * 4 + i) * KK + ntS * 16 + r] = saccM[ntS][i] + saccC[ntS][i];
}

// ---------------------------------------------------------------------------
// K3456 fused: per-b block does softmax (k3) -> interests GEMM (k4) ->
// w GEMM + top-k (k5) -> user GEMM (k6), all intermediates in LDS.
// Every arithmetic value and accumulation order is bit-identical to the
// separate-kernel pipeline (intermediates are the same f32 bits, just held
// in LDS instead of global). k4's A operand load+split hoisted out of the
// jj loop (mt = (wave+4*jj)&1 == wave&1 is jj-invariant -> it was redundant).
//
// LDS overlay (peak 47,616 B -> 3 blocks/CU; grid needs 2/CU):
//   [0,12800)        attn [KK][LH]      (phases A,B)  / shw [64][33] (C,D)
//   [12800,47616)    ls+red (A) / ht [256][34] (B) / I [32][260] pad (C,D)
// ---------------------------------------------------------------------------
__global__ __launch_bounds__(256) void k3456_fused(const float* __restrict__ Sg,
                                                   const int* __restrict__ ni,
                                                   const int* __restrict__ cc,
                                                   const float* __restrict__ H,
                                                   const float* __restrict__ cand,
                                                   float* __restrict__ out) {
    __shared__ __align__(16) char smem[47616];
    float*  attn_l = (float*)smem;               // [KK][LH]  = 12,800 B
    float*  ls     = (float*)(smem + 12800);     // [LH*KK]   = 12,800 B
    double* red    = (double*)(smem + 25600);    // [8][33]   =  2,112 B
    float*  ht     = (float*)(smem + 12800);     // [256][34] = 34,816 B
    float*  I_l    = (float*)(smem + 12800);     // [32][260] = 33,280 B (pad 4)
    float*  shw    = (float*)smem;               // [64][33]  =  8,448 B

    const int b = blockIdx.x;
    const int tid = threadIdx.x;
    const int wave = tid >> 6;
    const int lane = tid & 63;
    const int r = lane & 15, q = lane >> 4;
    const f32x4 zero = {0.f, 0.f, 0.f, 0.f};

    // ================= phase A: softmax over l per (b,k) (k3) ==============
    {
        const float* Sb = Sg + (size_t)b * LH * KK;
        for (int i = tid; i < LH * KK; i += 256) ls[i] = Sb[i];
        __syncthreads();

        const int k = tid & 31;
        const int grp = tid >> 5;
        const int nib = ni[b];

        double vals[13];
        int cnt = 0;
        double vmax = -1e300;
        for (int l = grp; l < LH; l += 8) {
            double v = (double)ls[l * KK + k];
            vals[cnt++] = v;
            vmax = fmax(vmax, v);
        }
        red[grp * 33 + k] = vmax;
        __syncthreads();
        if (grp == 0) {
            double m = red[k];
            for (int j = 1; j < 8; j++) m = fmax(m, red[j * 33 + k]);
            red[k] = m;
        }
        __syncthreads();
        const double mx = red[k];
        __syncthreads();

        double s = 0.0;
        for (int i = 0; i < cnt; i++) {
            double e = exp(vals[i] - mx);
            vals[i] = e;
            s += e;
        }
        red[grp * 33 + k] = s;
        __syncthreads();
        if (grp == 0) {
            double t = 0.0;
            for (int j = 0; j < 8; j++) t += red[j * 33 + k];
            red[k] = t;
        }
        __syncthreads();
        const double inv = 1.0 / red[k];

        float* ab = attn_l + k * LH;
        const bool masked = (k >= nib);
        cnt = 0;
        for (int l = grp; l < LH; l += 8) {
            ab[l] = masked ? 0.01f : (float)(vals[cnt] * inv);
            cnt++;
        }
    }
    __syncthreads();   // attn complete; ls/red dead (ht may now overwrite)

    // ================= phase B: I = attn @ H (k4, A-split hoisted) =========
    {
        const float* Hb = H + (size_t)b * LH * DD;
        const int mtB = wave & 1;          // jj-invariant (job = wave + 4*jj)
        const int m0B = mtB * 16;

        f32x4 accM[8], accC[8];
#pragma unroll
        for (int jj = 0; jj < 8; jj++) { accM[jj] = zero; accC[jj] = zero; }

        for (int ks = 0; ks < 4; ks++) {
            const int l0c = ks * 32;
            __syncthreads();
            // stage transposed H chunk: l in [l0c, l0c+32) -> ht[d][l-l0c]
            for (int u = tid; u < 32 * 64; u += 256) {
                const int l = u >> 6, dg = u & 63;
                float4 v = {0.f, 0.f, 0.f, 0.f};
                if (l0c + l < LH) v = *(const float4*)(Hb + (size_t)(l0c + l) * DD + dg * 4);
                ht[(dg * 4 + 0) * 34 + l] = v.x;
                ht[(dg * 4 + 1) * 34 + l] = v.y;
                ht[(dg * 4 + 2) * 34 + l] = v.z;
                ht[(dg * 4 + 3) * 34 + l] = v.w;
            }
            __syncthreads();

            // hoisted A (attn rows) load + split: same values for all jj
            float av[8];
#pragma unroll
            for (int j = 0; j < 8; j++) {
                const int l = l0c + q * 8 + j;
                av[j] = (l < LH) ? attn_l[(m0B + r) * LH + l] : 0.f;
            }
            bf16x8 ah, al, al2;
            split3x8(av, ah, al, al2);

#pragma unroll
            for (int jj = 0; jj < 8; jj++) {
                const int job = wave + jj * 4;
                const int nt = job >> 1;
                const int n0 = nt * 16;
                float bv[8];
                const float* hp = ht + (n0 + r) * 34 + q * 8;
#pragma unroll
                for (int j = 0; j < 8; j++) bv[j] = hp[j];
                bf16x8 bh, bl, bl2;
                split3x8(bv, bh, bl, bl2);
                mfma6(ah, al, al2, bh, bl, bl2, accM[jj], accC[jj]);
            }
        }
        __syncthreads();   // all waves done reading ht; I_l may overlay it

#pragma unroll
        for (int jj = 0; jj < 8; jj++) {
            const int job = wave + jj * 4;
            const int nt = job >> 1;
            const int n0 = nt * 16;
#pragma unroll
            for (int i = 0; i < 4; i++)
                I_l[(m0B + q * 4 + i) * 260 + n0 + r] = accM[jj][i] + accC[jj][i];
        }
    }
    __syncthreads();   // I complete; attn dead (shw may now overlay)

    // ================= phase C: w = cand @ I^T + top-k mask (k5) ===========
    {
        const float* Cb = cand + (size_t)b * NC * DD;

        for (int job = wave; job < 8; job += 4) {
            const int mt = job >> 1, nt = job & 1;
            const int m0 = mt * 16, n0 = nt * 16;
            f32x4 accM = zero, accC = zero;
#pragma unroll
            for (int ks = 0; ks < 8; ks++) {
                const float* ap = Cb + (size_t)(m0 + r) * DD + ks * 32 + q * 8;
                const float* bp = I_l + (n0 + r) * 260 + ks * 32 + q * 8;
                float4 u1 = *(const float4*)ap;      float4 u2 = *(const float4*)(ap + 4);
                float4 v1 = *(const float4*)bp;      float4 v2 = *(const float4*)(bp + 4);
                float av[8] = {u1.x,u1.y,u1.z,u1.w,u2.x,u2.y,u2.z,u2.w};
                float bv[8] = {v1.x,v1.y,v1.z,v1.w,v2.x,v2.y,v2.z,v2.w};
                bf16x8 ah, al, al2, bh, bl, bl2;
                split3x8(av, ah, al, al2);
                split3x8(bv, bh, bl, bl2);
                mfma6(ah, al, al2, bh, bl, bl2, accM, accC);
            }
#pragma unroll
            for (int i = 0; i < 4; i++) shw[(m0 + q * 4 + i) * 33 + n0 + r] = accM[i] + accC[i];
        }
        __syncthreads();

        if (tid < NC) {
            const int n = tid;
            int c8 = 8 * cc[b];
            int dynK = 32 - __clz(c8 - 1);
            dynK = min(max(dynK, 1), KK);
            float v[KK];
            for (int k = 0; k < KK; k++) v[k] = shw[n * 33 + k];
            for (int k = 0; k < KK; k++) {
                int rank = 0;
                for (int j = 0; j < KK; j++)
                    rank += (v[j] > v[k]) || (v[j] == v[k] && j < k);
                shw[n * 33 + k] = (rank < dynK) ? v[k] : 0.f;
            }
        }
    }
    __syncthreads();   // masked w complete

    // ================= phase D: user = w_masked @ I (k6) ===================
    {
        const int d = tid;
        float icol[KK];
#pragma unroll
        for (int k = 0; k < KK; k++) icol[k] = I_l[k * 260 + d];

        for (int n = 0; n < NC; n++) {
            const float* wr = shw + n * 33;
            float acc = 0.f;
#pragma unroll
            for (int k = 0; k < KK; k++) acc += wr[k] * icol[k];
            out[((size_t)b * NC + n) * DD + d] = acc;
        }
    }
}

// ---------------------------------------------------------------------------
extern "C" void kernel_launch(void* const* d_in, const int* in_sizes, int n_in,
                              void* d_out, int out_size, void* d_ws, size_t ws_size,
                              hipStream_t stream) {
    const float* hist = (const float*)d_in[0];
    const float* cand = (const float*)d_in[2];
    const int* ni = (const int*)d_in[3];
    const int* cc = (const int*)d_in[4];
    const float* W = (const float*)d_in[5];
    const float* C = (const float*)d_in[6];
    float* out = (float*)d_out;

    char* w8 = (char*)d_ws;
    float*  S   = (float*)(w8 + 0);
    bf16_t* Wh  = (bf16_t*)(w8 + OFF_WPL);
    bf16_t* Wl  = (bf16_t*)(w8 + OFF_WPL + 131072);
    bf16_t* Wl2 = (bf16_t*)(w8 + OFF_WPL + 262144);
    bf16_t* Ch  = (bf16_t*)(w8 + OFF_CPL);
    bf16_t* Cl  = (bf16_t*)(w8 + OFF_CPL + 16384);
    bf16_t* Cl2 = (bf16_t*)(w8 + OFF_CPL + 32768);

    kp_split<<<288, 256, 0, stream>>>(W, C, Wh, Wl, Wl2, Ch, Cl, Cl2);
    k12_proj_scores<<<800, 256, 0, stream>>>(hist, Wh, Wl, Wl2, Ch, Cl, Cl2, S);
    k3456_fused<<<BS, 256, 0, stream>>>(S, ni, cc, hist, cand, out);
}

// Round 4
// 286.471 us; speedup vs baseline: 1.4554x; 1.0429x over previous
//
#include <hip/hip_runtime.h>
#include <hip/hip_bf16.h>

typedef __bf16 bf16_t;
typedef __bf16 bf16x8 __attribute__((ext_vector_type(8)));
typedef float  f32x4  __attribute__((ext_vector_type(4)));

#define BS 512
#define LH 100
#define NC 64
#define DD 256
#define IC 256
#define KK 32

// workspace layout (bytes), peak 23,330,816 (proven-safe):
//  [0, 6,553,600)          S fp32 (k12 out, read by fused kernel)
//  [6,553,600, +393,216)   W bf16 planes
//  [6,946,816, +49,152)    C bf16 planes
#define OFF_WPL 6553600
#define OFF_CPL (6553600 + 3 * 131072)

// split fp32 into 3 bf16 terms: v == h + l + l2 exactly
__device__ __forceinline__ void split3(float v, bf16_t& h, bf16_t& l, bf16_t& l2) {
    h = (bf16_t)v;  float r1 = v - (float)h;
    l = (bf16_t)r1; float r2 = r1 - (float)l;
    l2 = (bf16_t)r2;
}

__device__ __forceinline__ void split3x8(const float* v, bf16x8& h, bf16x8& l, bf16x8& l2) {
#pragma unroll
    for (int j = 0; j < 8; j++) {
        bf16_t a, b, c;
        split3(v[j], a, b, c);
        h[j] = a; l[j] = b; l2[j] = c;
    }
}

// fp32-faithful 16x16x32 MFMA: 6 kept terms, main in accM, corrections in accC
__device__ __forceinline__ void mfma6(const bf16x8& ah, const bf16x8& al, const bf16x8& al2,
                                      const bf16x8& bh, const bf16x8& bl, const bf16x8& bl2,
                                      f32x4& accM, f32x4& accC) {
    accM = __builtin_amdgcn_mfma_f32_16x16x32_bf16(ah,  bh,  accM, 0, 0, 0);
    accC = __builtin_amdgcn_mfma_f32_16x16x32_bf16(ah,  bl,  accC, 0, 0, 0);
    accC = __builtin_amdgcn_mfma_f32_16x16x32_bf16(al,  bh,  accC, 0, 0, 0);
    accC = __builtin_amdgcn_mfma_f32_16x16x32_bf16(ah,  bl2, accC, 0, 0, 0);
    accC = __builtin_amdgcn_mfma_f32_16x16x32_bf16(al,  bl,  accC, 0, 0, 0);
    accC = __builtin_amdgcn_mfma_f32_16x16x32_bf16(al2, bh,  accC, 0, 0, 0);
}

// ---------------------------------------------------------------------------
// fast fp64 tanh: relative error < ~1e-15 (matches OCML tanh to the f32 ulp)
// ---------------------------------------------------------------------------
__device__ __forceinline__ float fast_tanh_f32(float xf) {
    const double t  = fabs((double)xf) * 2.0;              // t = 2|x| >= 0
    const double nf = rint(t * 1.4426950408889634);        // n = rint(t/ln2)
    double r = fma(nf, -6.93147180369123816490e-01, t);
    r = fma(nf, -1.90821492927058770002e-10, r);           // r in [-0.3466, 0.3466]
    const double r2 = r * r;
    double p =        2.08767569878680989792e-09;          // 1/12!
    p = fma(p, r,     2.50521083854417187751e-08);
    p = fma(p, r,     2.75573192239858906526e-07);
    p = fma(p, r,     2.75573192239858925110e-06);
    p = fma(p, r,     2.48015873015873015873e-05);
    p = fma(p, r,     1.98412698412698412526e-04);
    p = fma(p, r,     1.38888888888888894069e-03);
    p = fma(p, r,     8.33333333333333321769e-03);
    p = fma(p, r,     4.16666666666666643537e-02);
    p = fma(p, r,     1.66666666666666657415e-01);
    p = fma(p, r,     5.00000000000000000000e-01);
    const double q   = fma(r2, p, r);                      // expm1(r), no cancellation
    const double s   = ldexp(1.0, (int)nf);                // 2^n
    const double em1 = fma(s, q, s - 1.0);                 // e^t - 1
    double ti = em1 / (em1 + 2.0);                         // tanh(|x|)
    if (t > 20.0) ti = 1.0;
    return copysignf((float)ti, xf);
}

// ---------------------------------------------------------------------------
// KP: pre-split W (65536) and C (8192) fp32 -> 3 bf16 planes each
// ---------------------------------------------------------------------------
__global__ __launch_bounds__(256) void kp_split(const float* __restrict__ W,
                                                const float* __restrict__ C,
                                                bf16_t* __restrict__ Wh, bf16_t* __restrict__ Wl,
                                                bf16_t* __restrict__ Wl2,
                                                bf16_t* __restrict__ Ch, bf16_t* __restrict__ Cl,
                                                bf16_t* __restrict__ Cl2) {
    int idx = blockIdx.x * 256 + threadIdx.x;
    if (idx < 65536) {
        bf16_t h, l, l2;
        split3(W[idx], h, l, l2);
        Wh[idx] = h; Wl[idx] = l; Wl2[idx] = l2;
    } else {
        int i = idx - 65536;
        if (i < 8192) {
            bf16_t h, l, l2;
            split3(C[i], h, l, l2);
            Ch[i] = h; Cl[i] = l; Cl2[i] = l2;
        }
    }
}

// ---------------------------------------------------------------------------
// K12: P = tanh(H W^T) (fp32-faithful), S = P C^T (fp32-faithful).
// Round-4 change: grid 800x4waves -> 512x7waves (448 thr), one block per b.
//   800 blocks on 256 CUs = 3.125/CU: 32 CUs ran a 4th block while 224 idled
//   (~25% tail). Now exactly 2 blocks/CU, 14 waves/CU, zero tail. Each wave
//   owns one 16-row m-tile of this b's 100 rows (rows 100-111 computed and
//   discarded; per-row MFMA math is position-independent -> kept rows are
//   bit-identical). b=511/wave6 global-row clamp guards the only OOB.
// ---------------------------------------------------------------------------
#define WROW 280   // padded LDS row stride in bf16 (560B: 16B-aligned, 2-way banks)
__global__ __launch_bounds__(448) void k12_proj_scores(const float* __restrict__ H,
                                                       const bf16_t* __restrict__ Wh,
                                                       const bf16_t* __restrict__ Wl,
                                                       const bf16_t* __restrict__ Wl2,
                                                       const bf16_t* __restrict__ Ch,
                                                       const bf16_t* __restrict__ Cl,
                                                       const bf16_t* __restrict__ Cl2,
                                                       float* __restrict__ S) {
    __shared__ bf16_t wlds[3 * 16 * WROW];   // 26,880 B
    __shared__ float  pl[7][16 * 34];        // 15,232 B  (per-wave P pair-chunk)

    const int tid = threadIdx.x;
    const int wave = tid >> 6;               // 0..6
    const int lane = tid & 63;
    const int r = lane & 15, q = lane >> 4;
    const int b = blockIdx.x;
    const int lrow0 = wave * 16;             // local row of this wave's tile

    // ---- load + split A (H rows) once; clamp the single OOB case ----
    bf16x8 Ah[8], Al[8], Al2[8];
    {
        long grow = (long)b * LH + lrow0 + r;          // global H row
        const long maxrow = (long)BS * LH - 1;
        if (grow > maxrow) grow = maxrow;              // only b=511, wave 6
        const float* arow = H + (size_t)grow * DD + q * 8;
#pragma unroll
        for (int ks = 0; ks < 8; ks++) {
            const float* ap = arow + ks * 32;
            float4 u = *(const float4*)ap;
            float4 v = *(const float4*)(ap + 4);
            float av[8] = {u.x, u.y, u.z, u.w, v.x, v.y, v.z, v.w};
            split3x8(av, Ah[ks], Al[ks], Al2[ks]);
        }
    }

    const f32x4 zero = {0.f, 0.f, 0.f, 0.f};
    f32x4 saccM[2], saccC[2];
    saccM[0] = zero; saccM[1] = zero; saccC[0] = zero; saccC[1] = zero;

    float* myp = pl[wave];

    for (int c16 = 0; c16 < 16; c16++) {
        const int w0 = c16 * 16;             // first W row (= P output col) of chunk
        __syncthreads();   // protect wlds of previous chunk
        // ---- cooperative stage of W-plane chunk rows [w0, w0+16) ----
        for (int g = tid; g < 1536; g += 448) {
            const int p = g >> 9, rem = g & 511, row = rem >> 5, grp = rem & 31;
            const bf16_t* src = (p == 0) ? Wh : (p == 1) ? Wl : Wl2;
            bf16x8 v = *(const bf16x8*)(src + (size_t)(w0 + row) * DD + grp * 8);
            *(bf16x8*)(wlds + (p * 16 + row) * WROW + grp * 8) = v;
        }
        __syncthreads();

        // ---- stage 1: one 16-col P tile, full K ----
        f32x4 aM = zero, aC = zero;
#pragma unroll
        for (int ks = 0; ks < 8; ks++) {
            const int rowb = r * WROW + ks * 32 + q * 8;
            bf16x8 bh  = *(const bf16x8*)(wlds + 0 * 16 * WROW + rowb);
            bf16x8 bl  = *(const bf16x8*)(wlds + 1 * 16 * WROW + rowb);
            bf16x8 bl2 = *(const bf16x8*)(wlds + 2 * 16 * WROW + rowb);
            mfma6(Ah[ks], Al[ks], Al2[ks], bh, bl, bl2, aM, aC);
        }

        // ---- tanh -> per-wave pl (wave-local LDS round trip) ----
        const int colb = (c16 & 1) * 16;
#pragma unroll
        for (int i = 0; i < 4; i++) {
            float s1 = aM[i] + aC[i];
            myp[(q * 4 + i) * 34 + colb + r] = fast_tanh_f32(s1);
        }

        // ---- stage 2 on odd chunks: S += P_pair(32 cols) @ C_pair^T ----
        if (c16 & 1) {
            const int c0 = (c16 >> 1) * 32;
            const float* ps = myp + r * 34 + q * 8;
            float pv[8];
#pragma unroll
            for (int j = 0; j < 8; j++) pv[j] = ps[j];
            bf16x8 ph, plo, pl2;
            split3x8(pv, ph, plo, pl2);
#pragma unroll
            for (int ntS = 0; ntS < 2; ntS++) {
                const size_t base = (size_t)(ntS * 16 + r) * IC + c0 + q * 8;
                bf16x8 ch  = *(const bf16x8*)(Ch  + base);
                bf16x8 cl  = *(const bf16x8*)(Cl  + base);
                bf16x8 cl2 = *(const bf16x8*)(Cl2 + base);
                mfma6(ph, plo, pl2, ch, cl, cl2, saccM[ntS], saccC[ntS]);
            }
        }
    }

#pragma unroll
    for (int ntS = 0; ntS < 2; ntS++)
#pragma unroll
        for (int i = 0; i < 4; i++) {
            const int lrow = lrow0 + q * 4 + i;
            if (lrow < LH)
                S[((size_t)b * LH + lrow) * KK + ntS * 16 + r] = saccM[ntS][i] + saccC[ntS][i];
        }
}

// ---------------------------------------------------------------------------
// K3456 fused (512 threads, was 256): softmax (A) -> interests GEMM (B) ->
// w GEMM + top-k (C) -> user GEMM (D), intermediates in LDS.
// Phase A keeps the exact 256-thread shape (waves 4-7 idle through
// unconditional barriers) -> softmax bits unchanged. Phases B/C/D use all
// 8 waves; per-tile / per-(n,d) accumulation order unchanged -> output
// bit-identical to the 4-wave version. 16 waves/CU (was 8).
//
// LDS overlay (peak 47,616 B; 2 blocks/CU = 95 KB):
//   [0,12800)        attn [KK][LH]      (phases A,B)  / shw [64][33] (C,D)
//   [12800,47616)    ls+red (A) / ht [256][34] (B) / I [32][260] pad (C,D)
// ---------------------------------------------------------------------------
__global__ __launch_bounds__(512) void k3456_fused(const float* __restrict__ Sg,
                                                   const int* __restrict__ ni,
                                                   const int* __restrict__ cc,
                                                   const float* __restrict__ H,
                                                   const float* __restrict__ cand,
                                                   float* __restrict__ out) {
    __shared__ __align__(16) char smem[47616];
    float*  attn_l = (float*)smem;               // [KK][LH]  = 12,800 B
    float*  ls     = (float*)(smem + 12800);     // [LH*KK]   = 12,800 B
    double* red    = (double*)(smem + 25600);    // [8][33]   =  2,112 B
    float*  ht     = (float*)(smem + 12800);     // [256][34] = 34,816 B
    float*  I_l    = (float*)(smem + 12800);     // [32][260] = 33,280 B (pad 4)
    float*  shw    = (float*)smem;               // [64][33]  =  8,448 B

    const int b = blockIdx.x;
    const int tid = threadIdx.x;
    const int wave = tid >> 6;                   // 0..7
    const int lane = tid & 63;
    const int r = lane & 15, q = lane >> 4;
    const f32x4 zero = {0.f, 0.f, 0.f, 0.f};

    // ================= phase A: softmax over l per (b,k) (k3) ==============
    // Work done by tid<256 exactly as before; barriers executed by all.
    {
        const float* Sb = Sg + (size_t)b * LH * KK;
        for (int i = tid; i < LH * KK; i += 512) ls[i] = Sb[i];
        __syncthreads();

        const int k = tid & 31;
        const int grp = tid >> 5;                // 0..15; only grp<8 active
        const bool act = (grp < 8);
        const int nib = ni[b];

        double vals[13];
        int cnt = 0;
        if (act) {
            double vmax = -1e300;
            for (int l = grp; l < LH; l += 8) {
                double v = (double)ls[l * KK + k];
                vals[cnt++] = v;
                vmax = fmax(vmax, v);
            }
            red[grp * 33 + k] = vmax;
        }
        __syncthreads();
        if (tid < 32) {
            double m = red[k];
            for (int j = 1; j < 8; j++) m = fmax(m, red[j * 33 + k]);
            red[k] = m;
        }
        __syncthreads();
        const double mx = red[k];
        __syncthreads();

        if (act) {
            double s = 0.0;
            for (int i = 0; i < cnt; i++) {
                double e = exp(vals[i] - mx);
                vals[i] = e;
                s += e;
            }
            red[grp * 33 + k] = s;
        }
        __syncthreads();
        if (tid < 32) {
            double t = 0.0;
            for (int j = 0; j < 8; j++) t += red[j * 33 + k];
            red[k] = t;
        }
        __syncthreads();
        const double inv = 1.0 / red[k];

        if (act) {
            float* ab = attn_l + k * LH;
            const bool masked = (k >= nib);
            cnt = 0;
            for (int l = grp; l < LH; l += 8) {
                ab[l] = masked ? 0.01f : (float)(vals[cnt] * inv);
                cnt++;
            }
        }
    }
    __syncthreads();   // attn complete; ls/red dead (ht may now overwrite)

    // ================= phase B: I = attn @ H (k4) ==========================
    // 32 tiles (2 m x 16 n) over 8 waves x 4 jj (was 4 waves x 8 jj).
    // mt = (wave + 8*jj)&1 = wave&1 stays jj-invariant -> A-split hoisted.
    {
        const float* Hb = H + (size_t)b * LH * DD;
        const int mtB = wave & 1;
        const int m0B = mtB * 16;

        f32x4 accM[4], accC[4];
#pragma unroll
        for (int jj = 0; jj < 4; jj++) { accM[jj] = zero; accC[jj] = zero; }

        for (int ks = 0; ks < 4; ks++) {
            const int l0c = ks * 32;
            __syncthreads();
            // stage transposed H chunk: l in [l0c, l0c+32) -> ht[d][l-l0c]
            for (int u = tid; u < 32 * 64; u += 512) {
                const int l = u >> 6, dg = u & 63;
                float4 v = {0.f, 0.f, 0.f, 0.f};
                if (l0c + l < LH) v = *(const float4*)(Hb + (size_t)(l0c + l) * DD + dg * 4);
                ht[(dg * 4 + 0) * 34 + l] = v.x;
                ht[(dg * 4 + 1) * 34 + l] = v.y;
                ht[(dg * 4 + 2) * 34 + l] = v.z;
                ht[(dg * 4 + 3) * 34 + l] = v.w;
            }
            __syncthreads();

            // hoisted A (attn rows) load + split: same values for all jj
            float av[8];
#pragma unroll
            for (int j = 0; j < 8; j++) {
                const int l = l0c + q * 8 + j;
                av[j] = (l < LH) ? attn_l[(m0B + r) * LH + l] : 0.f;
            }
            bf16x8 ah, al, al2;
            split3x8(av, ah, al, al2);

#pragma unroll
            for (int jj = 0; jj < 4; jj++) {
                const int job = wave + jj * 8;
                const int nt = job >> 1;
                const int n0 = nt * 16;
                float bv[8];
                const float* hp = ht + (n0 + r) * 34 + q * 8;
#pragma unroll
                for (int j = 0; j < 8; j++) bv[j] = hp[j];
                bf16x8 bh, bl, bl2;
                split3x8(bv, bh, bl, bl2);
                mfma6(ah, al, al2, bh, bl, bl2, accM[jj], accC[jj]);
            }
        }
        __syncthreads();   // all waves done reading ht; I_l may overlay it

#pragma unroll
        for (int jj = 0; jj < 4; jj++) {
            const int job = wave + jj * 8;
            const int nt = job >> 1;
            const int n0 = nt * 16;
#pragma unroll
            for (int i = 0; i < 4; i++)
                I_l[(m0B + q * 4 + i) * 260 + n0 + r] = accM[jj][i] + accC[jj][i];
        }
    }
    __syncthreads();   // I complete; attn dead (shw may now overlay)

    // ================= phase C: w = cand @ I^T + top-k mask (k5) ===========
    // 8 tiles (4 m x 2 n) -> exactly 1 per wave (was 2 per wave).
    {
        const float* Cb = cand + (size_t)b * NC * DD;
        const int job = wave;
        const int mt = job >> 1, nt = job & 1;
        const int m0 = mt * 16, n0 = nt * 16;
        f32x4 accM = zero, accC = zero;
#pragma unroll
        for (int ks = 0; ks < 8; ks++) {
            const float* ap = Cb + (size_t)(m0 + r) * DD + ks * 32 + q * 8;
            const float* bp = I_l + (n0 + r) * 260 + ks * 32 + q * 8;
            float4 u1 = *(const float4*)ap;      float4 u2 = *(const float4*)(ap + 4);
            float4 v1 = *(const float4*)bp;      float4 v2 = *(const float4*)(bp + 4);
            float av[8] = {u1.x,u1.y,u1.z,u1.w,u2.x,u2.y,u2.z,u2.w};
            float bv[8] = {v1.x,v1.y,v1.z,v1.w,v2.x,v2.y,v2.z,v2.w};
            bf16x8 ah, al, al2, bh, bl, bl2;
            split3x8(av, ah, al, al2);
            split3x8(bv, bh, bl, bl2);
            mfma6(ah, al, al2, bh, bl, bl2, accM, accC);
        }
#pragma unroll
        for (int i = 0; i < 4; i++) shw[(m0 + q * 4 + i) * 33 + n0 + r] = accM[i] + accC[i];

        __syncthreads();

        if (tid < NC) {
            const int n = tid;
            int c8 = 8 * cc[b];
            int dynK = 32 - __clz(c8 - 1);
            dynK = min(max(dynK, 1), KK);
            float v[KK];
            for (int k = 0; k < KK; k++) v[k] = shw[n * 33 + k];
            for (int k = 0; k < KK; k++) {
                int rank = 0;
                for (int j = 0; j < KK; j++)
                    rank += (v[j] > v[k]) || (v[j] == v[k] && j < k);
                shw[n * 33 + k] = (rank < dynK) ? v[k] : 0.f;
            }
        }
    }
    __syncthreads();   // masked w complete

    // ================= phase D: user = w_masked @ I (k6) ===================
    // 512 threads: (nh, d) = (tid>>8, tid&255); each half does 32 n-rows.
    {
        const int d = tid & 255;
        const int nh = tid >> 8;
        float icol[KK];
#pragma unroll
        for (int k = 0; k < KK; k++) icol[k] = I_l[k * 260 + d];

        const int nend = nh * 32 + 32;
        for (int n = nh * 32; n < nend; n++) {
            const float* wr = shw + n * 33;
            float acc = 0.f;
#pragma unroll
            for (int k = 0; k < KK; k++) acc += wr[k] * icol[k];
            out[((size_t)b * NC + n) * DD + d] = acc;
        }
    }
}

// ---------------------------------------------------------------------------
extern "C" void kernel_launch(void* const* d_in, const int* in_sizes, int n_in,
                              void* d_out, int out_size, void* d_ws, size_t ws_size,
                              hipStream_t stream) {
    const float* hist = (const float*)d_in[0];
    const float* cand = (const float*)d_in[2];
    const int* ni = (const int*)d_in[3];
    const int* cc = (const int*)d_in[4];
    const float* W = (const float*)d_in[5];
    const float* C = (const float*)d_in[6];
    float* out = (float*)d_out;

    char* w8 = (char*)d_ws;
    float*  S   = (float*)(w8 + 0);
    bf16_t* Wh  = (bf16_t*)(w8 + OFF_WPL);
    bf16_t* Wl  = (bf16_t*)(w8 + OFF_WPL + 131072);
    bf16_t* Wl2 = (bf16_t*)(w8 + OFF_WPL + 262144);
    bf16_t* Ch  = (bf16_t*)(w8 + OFF_CPL);
    bf16_t* Cl  = (bf16_t*)(w8 + OFF_CPL + 16384);
    bf16_t* Cl2 = (bf16_t*)(w8 + OFF_CPL + 32768);

    kp_split<<<288, 256, 0, stream>>>(W, C, Wh, Wl, Wl2, Ch, Cl, Cl2);
    k12_proj_scores<<<BS, 448, 0, stream>>>(hist, Wh, Wl, Wl2, Ch, Cl, Cl2, S);
    k3456_fused<<<BS, 512, 0, stream>>>(S, ni, cc, hist, cand, out);
}

// Round 5
// 251.409 us; speedup vs baseline: 1.6584x; 1.1395x over previous
//
#include <hip/hip_runtime.h>
#include <hip/hip_bf16.h>

typedef __bf16 bf16_t;
typedef __bf16 bf16x8 __attribute__((ext_vector_type(8)));
typedef float  f32x4  __attribute__((ext_vector_type(4)));

#define BS 512
#define LH 100
#define NC 64
#define DD 256
#define IC 256
#define KK 32

// workspace layout (bytes), peak 23,330,816 (proven-safe):
//  [0, 6,553,600)          S fp32 (k12 out, read by fused kernel)
//  [6,553,600, +393,216)   W bf16 planes
//  [6,946,816, +49,152)    C bf16 planes
#define OFF_WPL 6553600
#define OFF_CPL (6553600 + 3 * 131072)

// split fp32 into 3 bf16 terms: v == h + l + l2 exactly
__device__ __forceinline__ void split3(float v, bf16_t& h, bf16_t& l, bf16_t& l2) {
    h = (bf16_t)v;  float r1 = v - (float)h;
    l = (bf16_t)r1; float r2 = r1 - (float)l;
    l2 = (bf16_t)r2;
}

__device__ __forceinline__ void split3x8(const float* v, bf16x8& h, bf16x8& l, bf16x8& l2) {
#pragma unroll
    for (int j = 0; j < 8; j++) {
        bf16_t a, b, c;
        split3(v[j], a, b, c);
        h[j] = a; l[j] = b; l2[j] = c;
    }
}

// fp32-faithful 16x16x32 MFMA: 6 kept terms, main in accM, corrections in accC
__device__ __forceinline__ void mfma6(const bf16x8& ah, const bf16x8& al, const bf16x8& al2,
                                      const bf16x8& bh, const bf16x8& bl, const bf16x8& bl2,
                                      f32x4& accM, f32x4& accC) {
    accM = __builtin_amdgcn_mfma_f32_16x16x32_bf16(ah,  bh,  accM, 0, 0, 0);
    accC = __builtin_amdgcn_mfma_f32_16x16x32_bf16(ah,  bl,  accC, 0, 0, 0);
    accC = __builtin_amdgcn_mfma_f32_16x16x32_bf16(al,  bh,  accC, 0, 0, 0);
    accC = __builtin_amdgcn_mfma_f32_16x16x32_bf16(ah,  bl2, accC, 0, 0, 0);
    accC = __builtin_amdgcn_mfma_f32_16x16x32_bf16(al,  bl,  accC, 0, 0, 0);
    accC = __builtin_amdgcn_mfma_f32_16x16x32_bf16(al2, bh,  accC, 0, 0, 0);
}

// ---------------------------------------------------------------------------
// fast fp64 tanh: relative error < ~1e-15 (matches OCML tanh to the f32 ulp)
// ---------------------------------------------------------------------------
__device__ __forceinline__ float fast_tanh_f32(float xf) {
    const double t  = fabs((double)xf) * 2.0;              // t = 2|x| >= 0
    const double nf = rint(t * 1.4426950408889634);        // n = rint(t/ln2)
    double r = fma(nf, -6.93147180369123816490e-01, t);
    r = fma(nf, -1.90821492927058770002e-10, r);           // r in [-0.3466, 0.3466]
    const double r2 = r * r;
    double p =        2.08767569878680989792e-09;          // 1/12!
    p = fma(p, r,     2.50521083854417187751e-08);
    p = fma(p, r,     2.75573192239858906526e-07);
    p = fma(p, r,     2.75573192239858925110e-06);
    p = fma(p, r,     2.48015873015873015873e-05);
    p = fma(p, r,     1.98412698412698412526e-04);
    p = fma(p, r,     1.38888888888888894069e-03);
    p = fma(p, r,     8.33333333333333321769e-03);
    p = fma(p, r,     4.16666666666666643537e-02);
    p = fma(p, r,     1.66666666666666657415e-01);
    p = fma(p, r,     5.00000000000000000000e-01);
    const double q   = fma(r2, p, r);                      // expm1(r), no cancellation
    const double s   = ldexp(1.0, (int)nf);                // 2^n
    const double em1 = fma(s, q, s - 1.0);                 // e^t - 1
    double ti = em1 / (em1 + 2.0);                         // tanh(|x|)
    if (t > 20.0) ti = 1.0;
    return copysignf((float)ti, xf);
}

// ---------------------------------------------------------------------------
// KP: pre-split W (65536) and C (8192) fp32 -> 3 bf16 planes each
// ---------------------------------------------------------------------------
__global__ __launch_bounds__(256) void kp_split(const float* __restrict__ W,
                                                const float* __restrict__ C,
                                                bf16_t* __restrict__ Wh, bf16_t* __restrict__ Wl,
                                                bf16_t* __restrict__ Wl2,
                                                bf16_t* __restrict__ Ch, bf16_t* __restrict__ Cl,
                                                bf16_t* __restrict__ Cl2) {
    int idx = blockIdx.x * 256 + threadIdx.x;
    if (idx < 65536) {
        bf16_t h, l, l2;
        split3(W[idx], h, l, l2);
        Wh[idx] = h; Wl[idx] = l; Wl2[idx] = l2;
    } else {
        int i = idx - 65536;
        if (i < 8192) {
            bf16_t h, l, l2;
            split3(C[i], h, l, l2);
            Ch[i] = h; Cl[i] = l; Cl2[i] = l2;
        }
    }
}

// ---------------------------------------------------------------------------
// K12: P = tanh(H W^T) (fp32-faithful), S = P C^T (fp32-faithful).
// Round-5 change (values & accumulation order bit-identical):
//  - DOUBLE-BUFFERED W staging with async split (T14): issue chunk c+1's
//    global loads BEFORE compute(c), ds_write them AFTER compute(c), ONE
//    barrier per chunk (was 2). Stage latency hides under 48 MFMAs + tanh.
//  - WROW padding replaced by XOR swizzle (byte ^= (row&7)<<4, identical on
//    write & read) so 2 chunk buffers + pl fit the 64KB static-LDS cap:
//    2*24,576 + 15,232 = 64,384 B. Swizzle spreads the 16-rows-same-column
//    b128 reads over 8 16B slots -> conflict-free (was 2-4 way).
//  - Hazard note: chunk-c writes to buffer nxt touch data last READ during
//    chunk c-1, which finished before the preceding barrier -> safe.
// ---------------------------------------------------------------------------
#define WCH 24576   // bytes per W-chunk buffer: 3 planes * 16 rows * 512 B
__global__ __launch_bounds__(448) void k12_proj_scores(const float* __restrict__ H,
                                                       const bf16_t* __restrict__ Wh,
                                                       const bf16_t* __restrict__ Wl,
                                                       const bf16_t* __restrict__ Wl2,
                                                       const bf16_t* __restrict__ Ch,
                                                       const bf16_t* __restrict__ Cl,
                                                       const bf16_t* __restrict__ Cl2,
                                                       float* __restrict__ S) {
    __shared__ __align__(16) char wbuf[2][WCH];   // 49,152 B
    __shared__ float pl[7][16 * 34];              // 15,232 B (per-wave P pair-chunk)

    const int tid = threadIdx.x;
    const int wave = tid >> 6;               // 0..6
    const int lane = tid & 63;
    const int r = lane & 15, q = lane >> 4;
    const int b = blockIdx.x;
    const int lrow0 = wave * 16;             // local row of this wave's tile

    // ---- per-thread staging-item constants (1536 16B items over 448 thr) ----
    // item g: plane p = g>>9, row = (g&511)>>5, grp = (g&511)&31
    // src elem off (within chunk, per plane) = row*DD + grp*8
    // dst byte off = (p*16+row)*512 + (grp*16 ^ ((row&7)<<4))
    const bf16_t* it_base[4];
    int it_src[4], it_dst[4];
#pragma unroll
    for (int it = 0; it < 4; it++) {
        const int g = tid + it * 448;
        const int p = (g >> 9) & 3, rem = g & 511, row = rem >> 5, grp = rem & 31;
        it_base[it] = (p == 0) ? Wh : (p == 1) ? Wl : Wl2;
        it_src[it] = row * DD + grp * 8;
        it_dst[it] = (p * 16 + row) * 512 + ((grp * 16) ^ ((row & 7) << 4));
    }
    const bool has4 = (tid < 192);           // 1536 = 3*448 + 192

    // ---- load + split A (H rows) once; clamp the single OOB case ----
    bf16x8 Ah[8], Al[8], Al2[8];
    {
        long grow = (long)b * LH + lrow0 + r;          // global H row
        const long maxrow = (long)BS * LH - 1;
        if (grow > maxrow) grow = maxrow;              // only b=511, wave 6
        const float* arow = H + (size_t)grow * DD + q * 8;
#pragma unroll
        for (int ks = 0; ks < 8; ks++) {
            const float* ap = arow + ks * 32;
            float4 u = *(const float4*)ap;
            float4 v = *(const float4*)(ap + 4);
            float av[8] = {u.x, u.y, u.z, u.w, v.x, v.y, v.z, v.w};
            split3x8(av, Ah[ks], Al[ks], Al2[ks]);
        }
    }

    const f32x4 zero = {0.f, 0.f, 0.f, 0.f};
    f32x4 saccM[2], saccC[2];
    saccM[0] = zero; saccM[1] = zero; saccC[0] = zero; saccC[1] = zero;

    float* myp = pl[wave];
    const int swz = (r & 7) << 4;

    // ---- prologue: stage chunk 0 into wbuf[0] ----
    {
        bf16x8 p0 = *(const bf16x8*)(it_base[0] + it_src[0]);
        bf16x8 p1 = *(const bf16x8*)(it_base[1] + it_src[1]);
        bf16x8 p2 = *(const bf16x8*)(it_base[2] + it_src[2]);
        bf16x8 p3;
        if (has4) p3 = *(const bf16x8*)(it_base[3] + it_src[3]);
        *(bf16x8*)(wbuf[0] + it_dst[0]) = p0;
        *(bf16x8*)(wbuf[0] + it_dst[1]) = p1;
        *(bf16x8*)(wbuf[0] + it_dst[2]) = p2;
        if (has4) *(bf16x8*)(wbuf[0] + it_dst[3]) = p3;
    }
    __syncthreads();

    for (int c16 = 0; c16 < 16; c16++) {
        const char* cur = wbuf[c16 & 1];
        char* nxt = wbuf[(c16 & 1) ^ 1];
        const bool pfv = (c16 < 15);

        // ---- issue next-chunk global loads (latency hides under compute) ----
        bf16x8 p0, p1, p2, p3;
        if (pfv) {
            const int co = (c16 + 1) * 16 * DD;   // element offset of next chunk
            p0 = *(const bf16x8*)(it_base[0] + co + it_src[0]);
            p1 = *(const bf16x8*)(it_base[1] + co + it_src[1]);
            p2 = *(const bf16x8*)(it_base[2] + co + it_src[2]);
            if (has4) p3 = *(const bf16x8*)(it_base[3] + co + it_src[3]);
        }

        // ---- stage 1: one 16-col P tile, full K (swizzled LDS reads) ----
        f32x4 aM = zero, aC = zero;
#pragma unroll
        for (int ks = 0; ks < 8; ks++) {
            const int colb = (ks * 64 + q * 16) ^ swz;
            const char* rowp = cur + r * 512 + colb;
            bf16x8 bh  = *(const bf16x8*)(rowp);
            bf16x8 bl  = *(const bf16x8*)(rowp + 8192);
            bf16x8 bl2 = *(const bf16x8*)(rowp + 16384);
            mfma6(Ah[ks], Al[ks], Al2[ks], bh, bl, bl2, aM, aC);
        }

        // ---- tanh -> per-wave pl (wave-local LDS round trip) ----
        const int colb2 = (c16 & 1) * 16;
#pragma unroll
        for (int i = 0; i < 4; i++) {
            float s1 = aM[i] + aC[i];
            myp[(q * 4 + i) * 34 + colb2 + r] = fast_tanh_f32(s1);
        }

        // ---- stage 2 on odd chunks: S += P_pair(32 cols) @ C_pair^T ----
        if (c16 & 1) {
            const int c0 = (c16 >> 1) * 32;
            const float* ps = myp + r * 34 + q * 8;
            float pv[8];
#pragma unroll
            for (int j = 0; j < 8; j++) pv[j] = ps[j];
            bf16x8 ph, plo, pl2;
            split3x8(pv, ph, plo, pl2);
#pragma unroll
            for (int ntS = 0; ntS < 2; ntS++) {
                const size_t base = (size_t)(ntS * 16 + r) * IC + c0 + q * 8;
                bf16x8 ch  = *(const bf16x8*)(Ch  + base);
                bf16x8 cl  = *(const bf16x8*)(Cl  + base);
                bf16x8 cl2 = *(const bf16x8*)(Cl2 + base);
                mfma6(ph, plo, pl2, ch, cl, cl2, saccM[ntS], saccC[ntS]);
            }
        }

        // ---- write prefetched chunk into the other buffer (late, T14) ----
        if (pfv) {
            *(bf16x8*)(nxt + it_dst[0]) = p0;
            *(bf16x8*)(nxt + it_dst[1]) = p1;
            *(bf16x8*)(nxt + it_dst[2]) = p2;
            if (has4) *(bf16x8*)(nxt + it_dst[3]) = p3;
        }
        __syncthreads();   // one barrier per chunk
    }

#pragma unroll
    for (int ntS = 0; ntS < 2; ntS++)
#pragma unroll
        for (int i = 0; i < 4; i++) {
            const int lrow = lrow0 + q * 4 + i;
            if (lrow < LH)
                S[((size_t)b * LH + lrow) * KK + ntS * 16 + r] = saccM[ntS][i] + saccC[ntS][i];
        }
}

// ---------------------------------------------------------------------------
// K3456 fused (512 threads): softmax (A) -> interests GEMM (B) ->
// w GEMM + top-k (C) -> user GEMM (D), intermediates in LDS.
// Unchanged from round 4 (bit-identical output).
//
// LDS overlay (peak 47,616 B; 2 blocks/CU = 95 KB):
//   [0,12800)        attn [KK][LH]      (phases A,B)  / shw [64][33] (C,D)
//   [12800,47616)    ls+red (A) / ht [256][34] (B) / I [32][260] pad (C,D)
// ---------------------------------------------------------------------------
__global__ __launch_bounds__(512) void k3456_fused(const float* __restrict__ Sg,
                                                   const int* __restrict__ ni,
                                                   const int* __restrict__ cc,
                                                   const float* __restrict__ H,
                                                   const float* __restrict__ cand,
                                                   float* __restrict__ out) {
    __shared__ __align__(16) char smem[47616];
    float*  attn_l = (float*)smem;               // [KK][LH]  = 12,800 B
    float*  ls     = (float*)(smem + 12800);     // [LH*KK]   = 12,800 B
    double* red    = (double*)(smem + 25600);    // [8][33]   =  2,112 B
    float*  ht     = (float*)(smem + 12800);     // [256][34] = 34,816 B
    float*  I_l    = (float*)(smem + 12800);     // [32][260] = 33,280 B (pad 4)
    float*  shw    = (float*)smem;               // [64][33]  =  8,448 B

    const int b = blockIdx.x;
    const int tid = threadIdx.x;
    const int wave = tid >> 6;                   // 0..7
    const int lane = tid & 63;
    const int r = lane & 15, q = lane >> 4;
    const f32x4 zero = {0.f, 0.f, 0.f, 0.f};

    // ================= phase A: softmax over l per (b,k) (k3) ==============
    {
        const float* Sb = Sg + (size_t)b * LH * KK;
        for (int i = tid; i < LH * KK; i += 512) ls[i] = Sb[i];
        __syncthreads();

        const int k = tid & 31;
        const int grp = tid >> 5;                // 0..15; only grp<8 active
        const bool act = (grp < 8);
        const int nib = ni[b];

        double vals[13];
        int cnt = 0;
        if (act) {
            double vmax = -1e300;
            for (int l = grp; l < LH; l += 8) {
                double v = (double)ls[l * KK + k];
                vals[cnt++] = v;
                vmax = fmax(vmax, v);
            }
            red[grp * 33 + k] = vmax;
        }
        __syncthreads();
        if (tid < 32) {
            double m = red[k];
            for (int j = 1; j < 8; j++) m = fmax(m, red[j * 33 + k]);
            red[k] = m;
        }
        __syncthreads();
        const double mx = red[k];
        __syncthreads();

        if (act) {
            double s = 0.0;
            for (int i = 0; i < cnt; i++) {
                double e = exp(vals[i] - mx);
                vals[i] = e;
                s += e;
            }
            red[grp * 33 + k] = s;
        }
        __syncthreads();
        if (tid < 32) {
            double t = 0.0;
            for (int j = 0; j < 8; j++) t += red[j * 33 + k];
            red[k] = t;
        }
        __syncthreads();
        const double inv = 1.0 / red[k];

        if (act) {
            float* ab = attn_l + k * LH;
            const bool masked = (k >= nib);
            cnt = 0;
            for (int l = grp; l < LH; l += 8) {
                ab[l] = masked ? 0.01f : (float)(vals[cnt] * inv);
                cnt++;
            }
        }
    }
    __syncthreads();   // attn complete; ls/red dead (ht may now overwrite)

    // ================= phase B: I = attn @ H (k4) ==========================
    {
        const float* Hb = H + (size_t)b * LH * DD;
        const int mtB = wave & 1;
        const int m0B = mtB * 16;

        f32x4 accM[4], accC[4];
#pragma unroll
        for (int jj = 0; jj < 4; jj++) { accM[jj] = zero; accC[jj] = zero; }

        for (int ks = 0; ks < 4; ks++) {
            const int l0c = ks * 32;
            __syncthreads();
            // stage transposed H chunk: l in [l0c, l0c+32) -> ht[d][l-l0c]
            for (int u = tid; u < 32 * 64; u += 512) {
                const int l = u >> 6, dg = u & 63;
                float4 v = {0.f, 0.f, 0.f, 0.f};
                if (l0c + l < LH) v = *(const float4*)(Hb + (size_t)(l0c + l) * DD + dg * 4);
                ht[(dg * 4 + 0) * 34 + l] = v.x;
                ht[(dg * 4 + 1) * 34 + l] = v.y;
                ht[(dg * 4 + 2) * 34 + l] = v.z;
                ht[(dg * 4 + 3) * 34 + l] = v.w;
            }
            __syncthreads();

            // hoisted A (attn rows) load + split: same values for all jj
            float av[8];
#pragma unroll
            for (int j = 0; j < 8; j++) {
                const int l = l0c + q * 8 + j;
                av[j] = (l < LH) ? attn_l[(m0B + r) * LH + l] : 0.f;
            }
            bf16x8 ah, al, al2;
            split3x8(av, ah, al, al2);

#pragma unroll
            for (int jj = 0; jj < 4; jj++) {
                const int job = wave + jj * 8;
                const int nt = job >> 1;
                const int n0 = nt * 16;
                float bv[8];
                const float* hp = ht + (n0 + r) * 34 + q * 8;
#pragma unroll
                for (int j = 0; j < 8; j++) bv[j] = hp[j];
                bf16x8 bh, bl, bl2;
                split3x8(bv, bh, bl, bl2);
                mfma6(ah, al, al2, bh, bl, bl2, accM[jj], accC[jj]);
            }
        }
        __syncthreads();   // all waves done reading ht; I_l may overlay it

#pragma unroll
        for (int jj = 0; jj < 4; jj++) {
            const int job = wave + jj * 8;
            const int nt = job >> 1;
            const int n0 = nt * 16;
#pragma unroll
            for (int i = 0; i < 4; i++)
                I_l[(m0B + q * 4 + i) * 260 + n0 + r] = accM[jj][i] + accC[jj][i];
        }
    }
    __syncthreads();   // I complete; attn dead (shw may now overlay)

    // ================= phase C: w = cand @ I^T + top-k mask (k5) ===========
    {
        const float* Cb = cand + (size_t)b * NC * DD;
        const int job = wave;
        const int mt = job >> 1, nt = job & 1;
        const int m0 = mt * 16, n0 = nt * 16;
        f32x4 accM = zero, accC = zero;
#pragma unroll
        for (int ks = 0; ks < 8; ks++) {
            const float* ap = Cb + (size_t)(m0 + r) * DD + ks * 32 + q * 8;
            const float* bp = I_l + (n0 + r) * 260 + ks * 32 + q * 8;
            float4 u1 = *(const float4*)ap;      float4 u2 = *(const float4*)(ap + 4);
            float4 v1 = *(const float4*)bp;      float4 v2 = *(const float4*)(bp + 4);
            float av[8] = {u1.x,u1.y,u1.z,u1.w,u2.x,u2.y,u2.z,u2.w};
            float bv[8] = {v1.x,v1.y,v1.z,v1.w,v2.x,v2.y,v2.z,v2.w};
            bf16x8 ah, al, al2, bh, bl, bl2;
            split3x8(av, ah, al, al2);
            split3x8(bv, bh, bl, bl2);
            mfma6(ah, al, al2, bh, bl, bl2, accM, accC);
        }
#pragma unroll
        for (int i = 0; i < 4; i++) shw[(m0 + q * 4 + i) * 33 + n0 + r] = accM[i] + accC[i];

        __syncthreads();

        if (tid < NC) {
            const int n = tid;
            int c8 = 8 * cc[b];
            int dynK = 32 - __clz(c8 - 1);
            dynK = min(max(dynK, 1), KK);
            float v[KK];
            for (int k = 0; k < KK; k++) v[k] = shw[n * 33 + k];
            for (int k = 0; k < KK; k++) {
                int rank = 0;
                for (int j = 0; j < KK; j++)
                    rank += (v[j] > v[k]) || (v[j] == v[k] && j < k);
                shw[n * 33 + k] = (rank < dynK) ? v[k] : 0.f;
            }
        }
    }
    __syncthreads();   // masked w complete

    // ================= phase D: user = w_masked @ I (k6) ===================
    {
        const int d = tid & 255;
        const int nh = tid >> 8;
        float icol[KK];
#pragma unroll
        for (int k = 0; k < KK; k++) icol[k] = I_l[k * 260 + d];

        const int nend = nh * 32 + 32;
        for (int n = nh * 32; n < nend; n++) {
            const float* wr = shw + n * 33;
            float acc = 0.f;
#pragma unroll
            for (int k = 0; k < KK; k++) acc += wr[k] * icol[k];
            out[((size_t)b * NC + n) * DD + d] = acc;
        }
    }
}

// ---------------------------------------------------------------------------
extern "C" void kernel_launch(void* const* d_in, const int* in_sizes, int n_in,
                              void* d_out, int out_size, void* d_ws, size_t ws_size,
                              hipStream_t stream) {
    const float* hist = (const float*)d_in[0];
    const float* cand = (const float*)d_in[2];
    const int* ni = (const int*)d_in[3];
    const int* cc = (const int*)d_in[4];
    const float* W = (const float*)d_in[5];
    const float* C = (const float*)d_in[6];
    float* out = (float*)d_out;

    char* w8 = (char*)d_ws;
    float*  S   = (float*)(w8 + 0);
    bf16_t* Wh  = (bf16_t*)(w8 + OFF_WPL);
    bf16_t* Wl  = (bf16_t*)(w8 + OFF_WPL + 131072);
    bf16_t* Wl2 = (bf16_t*)(w8 + OFF_WPL + 262144);
    bf16_t* Ch  = (bf16_t*)(w8 + OFF_CPL);
    bf16_t* Cl  = (bf16_t*)(w8 + OFF_CPL + 16384);
    bf16_t* Cl2 = (bf16_t*)(w8 + OFF_CPL + 32768);

    kp_split<<<288, 256, 0, stream>>>(W, C, Wh, Wl, Wl2, Ch, Cl, Cl2);
    k12_proj_scores<<<BS, 448, 0, stream>>>(hist, Wh, Wl, Wl2, Ch, Cl, Cl2, S);
    k3456_fused<<<BS, 512, 0, stream>>>(S, ni, cc, hist, cand, out);
}